// Round 12
// baseline (2818.702 us; speedup 1.0000x reference)
//
#include <hip/hip_runtime.h>

#define LL 128      // memory length
#define BB 16       // batch
#define HH 512      // hidden
#define VV 16000    // vocab
#define TT 32       // steps
#define NH 8        // heads
#define DK 64       // head dim
#define NBLK 250    // mega grid (1 block/CU, co-resident)
#define NTHR 1024

// workspace layout (float offsets)
#define WS_K 0                                   // K[b][h][l][64] tiles
#define WS_V (BB*NH*LL*DK)                       // V same
#define WS_CTXB (2*BB*NH*LL*DK)                  // ctx [b][k]        (sc-only)
#define WS_HS0 (WS_CTXB + BB*HH)                 // h [k][b] ping     (sc-only)
#define WS_HS1 (WS_HS0 + BB*HH)
#define WS_HBK0 (WS_HS1 + BB*HH)                 // h [b][k] ping
#define WS_HBK1 (WS_HBK0 + BB*HH)
#define WS_P (WS_HBK1 + BB*HH)                   // p[b][h][128]      (sc-only)
#define WS_CAND (WS_P + BB*NH*LL)                // u64 cand[256][16] (sc-only)
#define WS_ARR (WS_CAND + 2*256*BB)              // u32 arrive[256]
#define WS_SENSE (WS_ARR + 256)                  // u32

#define OUT_HID_OFF ((size_t)TT*BB*VV)
#define OUT_SC_OFF  (OUT_HID_OFF + (size_t)TT*BB*HH)

typedef float v4f __attribute__((ext_vector_type(4)));
typedef unsigned long long u64;

__device__ __forceinline__ u64 u64max(u64 a, u64 b) { return a > b ? a : b; }

// ---- 16B cache-bypassing (sc0+sc1 -> coherent at LLC) load/store helpers ----
__device__ __forceinline__ float4 ldnc4(const float* p) {
    v4f r;
    asm volatile("global_load_dwordx4 %0, %1, off sc0 sc1\n\t"
                 "s_waitcnt vmcnt(0)"
                 : "=&v"(r) : "v"(p) : "memory");
    return make_float4(r.x, r.y, r.z, r.w);
}
__device__ __forceinline__ void ldnc4x2(const float* p0, const float* p1,
                                        float4& a, float4& b) {
    v4f ra, rb;
    asm volatile("global_load_dwordx4 %0, %2, off sc0 sc1\n\t"
                 "global_load_dwordx4 %1, %3, off sc0 sc1\n\t"
                 "s_waitcnt vmcnt(0)"
                 : "=&v"(ra), "=&v"(rb) : "v"(p0), "v"(p1) : "memory");
    a = make_float4(ra.x, ra.y, ra.z, ra.w);
    b = make_float4(rb.x, rb.y, rb.z, rb.w);
}
__device__ __forceinline__ void ldnc8x4(const u64* p0, const u64* p1,
        const u64* p2, const u64* p3, u64& a, u64& b, u64& c, u64& d) {
    asm volatile("global_load_dwordx2 %0, %4, off sc0 sc1\n\t"
                 "global_load_dwordx2 %1, %5, off sc0 sc1\n\t"
                 "global_load_dwordx2 %2, %6, off sc0 sc1\n\t"
                 "global_load_dwordx2 %3, %7, off sc0 sc1\n\t"
                 "s_waitcnt vmcnt(0)"
                 : "=&v"(a), "=&v"(b), "=&v"(c), "=&v"(d)
                 : "v"(p0), "v"(p1), "v"(p2), "v"(p3) : "memory");
}
__device__ __forceinline__ void ldu32x4(const unsigned* p0, const unsigned* p1,
        const unsigned* p2, const unsigned* p3,
        unsigned& a, unsigned& b, unsigned& c, unsigned& d) {
    asm volatile("global_load_dword %0, %4, off sc0 sc1\n\t"
                 "global_load_dword %1, %5, off sc0 sc1\n\t"
                 "global_load_dword %2, %6, off sc0 sc1\n\t"
                 "global_load_dword %3, %7, off sc0 sc1\n\t"
                 "s_waitcnt vmcnt(0)"
                 : "=&v"(a), "=&v"(b), "=&v"(c), "=&v"(d)
                 : "v"(p0), "v"(p1), "v"(p2), "v"(p3) : "memory");
}
__device__ __forceinline__ void stnc4(float* p, float4 v) {
    v4f r; r.x = v.x; r.y = v.y; r.z = v.z; r.w = v.w;
    asm volatile("global_store_dwordx4 %0, %1, off sc0 sc1"
                 :: "v"(p), "v"(r) : "memory");
}
__device__ __forceinline__ void stnc1(float* p, float v) {
    asm volatile("global_store_dword %0, %1, off sc0 sc1"
                 :: "v"(p), "v"(v) : "memory");
}

// ------ kv projection (per-(b,h) tiled output) + per-call init -------------
__global__ __launch_bounds__(256) void kv_kernel(const float* __restrict__ mem,
        const float* __restrict__ Wk, const float* __restrict__ bk,
        const float* __restrict__ Wv, const float* __restrict__ bv,
        float* __restrict__ ws) {
    int blk = blockIdx.x;
    int tid = threadIdx.x;
    int rg = blk >> 4, ct = blk & 15;
    int isV = ct >= 8;
    int h = ct & 7;
    int colbase = h * 64;
    const float* W = isV ? Wv : Wk;
    const float* bias = isV ? bv : bk;
    float* outp = ws + (isV ? WS_V : WS_K);
    int rowbase = rg * 16;
    __shared__ float As[16*516];

    {
        const float4* srcp = (const float4*)(mem + (size_t)rowbase*512);
        #pragma unroll
        for (int j = 0; j < 8; ++j) {
            int i = tid + 256*j;
            float4 v = srcp[i];
            int row = i >> 7, c4i = i & 127;
            *(float4*)(As + row*516 + c4i*4) = v;
        }
    }
    if (blk == 0) {   // per-call init
        for (int i = tid; i < BB*HH; i += 256) {
            ws[WS_HS0 + i] = 0.f;
            ws[WS_HBK0 + i] = 0.f;
        }
        u64* cand = (u64*)(ws + WS_CAND);
        for (int i = tid; i < 256*BB; i += 256) cand[i] = 0ull;
        unsigned* arrive = (unsigned*)(ws + WS_ARR);
        for (int i = tid; i < 256; i += 256)
            arrive[i] = (i == 0 || i >= NBLK) ? 0x7FFFFFFFu : 0u;
        if (tid == 0) *(unsigned*)(ws + WS_SENSE) = 0u;
    }
    __syncthreads();

    int cq = tid & 15;
    int rq4 = (tid >> 4) & 3;
    int kq = tid >> 6;
    float acc[4][4];
    #pragma unroll
    for (int i = 0; i < 4; ++i) { acc[i][0]=0.f; acc[i][1]=0.f; acc[i][2]=0.f; acc[i][3]=0.f; }
    const float* wp = W + colbase + cq*4;
    for (int k4 = kq*32; k4 < kq*32 + 32; ++k4) {
        float4 a0 = *(const float4*)(As + (rq4*4+0)*516 + k4*4);
        float4 a1 = *(const float4*)(As + (rq4*4+1)*516 + k4*4);
        float4 a2 = *(const float4*)(As + (rq4*4+2)*516 + k4*4);
        float4 a3 = *(const float4*)(As + (rq4*4+3)*516 + k4*4);
        const float* wrow = wp + (size_t)(4*k4)*512;
        float4 w0 = *(const float4*)(wrow);
        float4 w1 = *(const float4*)(wrow + 512);
        float4 w2 = *(const float4*)(wrow + 1024);
        float4 w3 = *(const float4*)(wrow + 1536);
        #define KV_FMA(ri, A) \
            acc[ri][0] += A.x*w0.x + A.y*w1.x + A.z*w2.x + A.w*w3.x; \
            acc[ri][1] += A.x*w0.y + A.y*w1.y + A.z*w2.y + A.w*w3.y; \
            acc[ri][2] += A.x*w0.z + A.y*w1.z + A.z*w2.z + A.w*w3.z; \
            acc[ri][3] += A.x*w0.w + A.y*w1.w + A.z*w2.w + A.w*w3.w;
        KV_FMA(0, a0) KV_FMA(1, a1) KV_FMA(2, a2) KV_FMA(3, a3)
        #undef KV_FMA
    }
    __syncthreads();
    float* red = As;
    #pragma unroll
    for (int ri = 0; ri < 4; ++ri)
        *(float4*)(red + ri*1024 + tid*4) =
            make_float4(acc[ri][0], acc[ri][1], acc[ri][2], acc[ri][3]);
    __syncthreads();
    {
        int c4 = tid & 15, row = tid >> 4;
        int rq = row >> 2, ri = row & 3;
        float4 b4v = *(const float4*)(bias + colbase + c4*4);
        float o[4] = {b4v.x, b4v.y, b4v.z, b4v.w};
        #pragma unroll
        for (int kq2 = 0; kq2 < 4; ++kq2) {
            const float* pr = red + ri*1024 + (kq2*64 + rq*16 + c4)*4;
            o[0] += pr[0]; o[1] += pr[1]; o[2] += pr[2]; o[3] += pr[3];
        }
        int R = rowbase + row;
        int l = R >> 4, b = R & 15;
        *(float4*)(outp + ((size_t)(b*NH + h)*LL + l)*DK + c4*4) =
            make_float4(o[0], o[1], o[2], o[3]);
    }
}

// ---- grid barrier: store-arrive + block-0 wave scan (no RMW contention) ----
__device__ __forceinline__ void gridbar(float* ws, unsigned target) {
    unsigned* arrive = (unsigned*)(ws + WS_ARR);
    unsigned* sense  = (unsigned*)(ws + WS_SENSE);
    asm volatile("s_waitcnt vmcnt(0)" ::: "memory");
    __syncthreads();
    if (blockIdx.x == 0) {
        if (threadIdx.x < 64) {
            const unsigned* ap = arrive + threadIdx.x;
            for (;;) {
                unsigned a0, a1, a2, a3;
                ldu32x4(ap, ap + 64, ap + 128, ap + 192, a0, a1, a2, a3);
                bool ok = (int)(a0 - target) >= 0 && (int)(a1 - target) >= 0 &&
                          (int)(a2 - target) >= 0 && (int)(a3 - target) >= 0;
                if (__all(ok)) break;
                __builtin_amdgcn_s_sleep(2);
            }
            if (threadIdx.x == 0)
                __hip_atomic_store(sense, target, __ATOMIC_RELAXED,
                                   __HIP_MEMORY_SCOPE_AGENT);
        }
    } else if (threadIdx.x == 0) {
        __hip_atomic_store(&arrive[blockIdx.x], target, __ATOMIC_RELAXED,
                           __HIP_MEMORY_SCOPE_AGENT);
        while ((int)(__hip_atomic_load(sense, __ATOMIC_RELAXED,
                     __HIP_MEMORY_SCOPE_AGENT) - target) < 0)
            __builtin_amdgcn_s_sleep(2);
    }
    __syncthreads();
}

// ---------------- mega kernel: all 32 steps ----------------
__global__ __launch_bounds__(NTHR) void mega_kernel(
        const float* __restrict__ emb, const float* __restrict__ Wq,
        const float* __restrict__ bq,
        const float* __restrict__ Wih, const float* __restrict__ bih,
        const float* __restrict__ Whh, const float* __restrict__ bhh,
        const float* __restrict__ Wf,  const float* __restrict__ bf,
        const int* __restrict__ olen, float* __restrict__ ws,
        float* __restrict__ out) {
    // LDS arena, 144 KB total; layout depends on block class.
    // blk<128 : [K 32K][V 32K][wf(16c) 32K][hs 32K][scr 16K]
    // blk>=128: [wf(48c) 96K]              [hs 32K][scr 16K]
    __shared__ __align__(16) char arena[147456];
    int blk = blockIdx.x, tid = threadIdx.x;
    int colbase = blk * 64;
    bool classA = blk < 128;
    float* kvK = (float*)arena;
    float* kvV = kvK + 8192;
    float* wf  = classA ? (float*)(arena + 65536) : (float*)arena;
    float* hs_s = (float*)(arena + 98304);
    float* scr  = (float*)(arena + 131072);
    u64* cand = (u64*)(ws + WS_CAND);
    unsigned bno = 0;
    int b = blk >> 3, h = blk & 7;          // attn identity (classA)

    if (classA) {   // one-time: K (swizzled) + V + 16 Wf cols into LDS
        const float* Ksrc = ws + WS_K + (size_t)(b*NH + h)*LL*DK;
        const float* Vsrc = ws + WS_V + (size_t)(b*NH + h)*LL*DK;
        #pragma unroll
        for (int j = 0; j < 2; ++j) {
            int i4 = tid + 1024*j;              // 2048 float4 each
            int l = i4 >> 4, c = (i4 & 15)*4;
            int cs = c ^ ((l & 7) << 3);
            *(float4*)(kvK + l*64 + cs) = *(const float4*)(Ksrc + (size_t)l*64 + c);
            *(float4*)(kvV + l*64 + c)  = *(const float4*)(Vsrc + (size_t)l*64 + c);
        }
        #pragma unroll
        for (int j = 0; j < 2; ++j) {
            int i4 = tid + 1024*j;              // 2048 float4: 16 cols
            int k = i4 >> 2, c4 = i4 & 3;
            *(float4*)(wf + k*16 + c4*4) =
                *(const float4*)(Wf + (size_t)k*VV + colbase + c4*4);
        }
    } else {        // 48 Wf cols into LDS
        #pragma unroll
        for (int j = 0; j < 6; ++j) {
            int i = tid + 1024*j;               // 6144 float4
            int p = i >> 11, rem = i & 2047;
            int k = rem >> 2, c4 = rem & 3;
            *(float4*)(wf + (p*512 + k)*16 + c4*4) =
                *(const float4*)(Wf + (size_t)k*VV + colbase + p*16 + c4*4);
        }
    }
    __syncthreads();

    for (int t = 0; t < TT; ++t) {
        const float* hs_prev  = ws + ((t & 1) ? WS_HS1  : WS_HS0);
        float*       hs_new   = ws + ((t & 1) ? WS_HS0  : WS_HS1);
        const float* hbk_prev = ws + ((t & 1) ? WS_HBK1 : WS_HBK0);
        float*       hbk_new  = ws + ((t & 1) ? WS_HBK0 : WS_HBK1);

        // ================= P1: attention (blocks 0..127) =================
        if (classA) {
            float* q    = scr;                    // 1024
            float* buf  = scr + 1024;             // 1024
            float* qh   = scr + 2048;             // 64
            float* pbuf = scr + 2112;             // 128
            float* ctxv = scr + 2240;             // 64

            if (t > 0) {   // argmax from 256 (padded) candidates
                if (tid < 64) {
                    const u64* cp = cand + b;
                    u64 a0, a1, a2, a3;
                    ldnc8x4(cp + (size_t)tid*BB, cp + (size_t)(tid+64)*BB,
                            cp + (size_t)(tid+128)*BB, cp + (size_t)(tid+192)*BB,
                            a0, a1, a2, a3);
                    u64 m = u64max(u64max(a0, a1), u64max(a2, a3));
                    #pragma unroll
                    for (int off = 32; off; off >>= 1)
                        m = u64max(m, (u64)__shfl_xor((long long)m, off));
                    if (tid == 0)
                        *(unsigned*)(scr + 2304) = 0xFFFFFFFFu - (unsigned)(m & 0xFFFFFFFFull);
                }
                __syncthreads();
            }
            unsigned idx = (t > 0) ? *(unsigned*)(scr + 2304) : 0u;
            if (tid < 128) {
                *(float4*)(q + tid*4) = ((const float4*)emb)[(size_t)idx*128 + tid];
            } else if (tid < 256) {
                int j = tid - 128;
                *(float4*)(q + 512 + j*4) = ldnc4(hbk_prev + (size_t)b*HH + j*4);
            }
            __syncthreads();

            {   // qproj (Wq cached): c4 = tid&15 (4 cols), kc = tid>>4, k = kc+64i
                int c4 = tid & 15, kc = tid >> 4;
                const float* wp = Wq + (size_t)kc*HH + h*64 + c4*4;
                float ax=0.f, ay=0.f, az=0.f, aw=0.f;
                #pragma unroll
                for (int i = 0; i < 16; ++i) {
                    float x = q[kc + 64*i];
                    float4 w4 = *(const float4*)wp;
                    wp += (size_t)64*HH;
                    ax += x*w4.x; ay += x*w4.y; az += x*w4.z; aw += x*w4.w;
                }
                float v;
                v = ax; v += __shfl_xor(v,16); v += __shfl_xor(v,32); ax = v;
                v = ay; v += __shfl_xor(v,16); v += __shfl_xor(v,32); ay = v;
                v = az; v += __shfl_xor(v,16); v += __shfl_xor(v,32); az = v;
                v = aw; v += __shfl_xor(v,16); v += __shfl_xor(v,32); aw = v;
                int wv = tid >> 6;
                if ((tid & 48) == 0)
                    *(float4*)(buf + wv*64 + c4*4) = make_float4(ax, ay, az, aw);
            }
            __syncthreads();
            if (tid < 64) {
                float s = bq[h*64 + tid];
                #pragma unroll
                for (int wv = 0; wv < 16; ++wv) s += buf[wv*64 + tid];
                qh[tid] = s;
            }
            __syncthreads();

            {   // scores from swizzled K LDS: l = tid&127, jh = tid>>7 (8 k each)
                int l = tid & 127, jh = tid >> 7;
                int sw = (l & 7) << 3;
                float4 k0 = *(const float4*)(kvK + l*64 + ((jh*8) ^ sw));
                float4 k1 = *(const float4*)(kvK + l*64 + ((jh*8 + 4) ^ sw));
                const float4* q4 = (const float4*)qh + jh*2;
                float4 q0 = q4[0], q1 = q4[1];
                buf[jh*128 + l] = q0.x*k0.x + q0.y*k0.y + q0.z*k0.z + q0.w*k0.w
                                + q1.x*k1.x + q1.y*k1.y + q1.z*k1.z + q1.w*k1.w;
            }
            __syncthreads();

            if (tid < 64) {   // softmax over 128 (wave 0)
                float s0v = 0.f, s1v = 0.f;
                #pragma unroll
                for (int jh = 0; jh < 8; ++jh) {
                    s0v += buf[jh*128 + tid];
                    s1v += buf[jh*128 + 64 + tid];
                }
                s0v *= 0.125f; s1v *= 0.125f;
                float m = fmaxf(s0v, s1v);
                #pragma unroll
                for (int off = 32; off; off >>= 1) m = fmaxf(m, __shfl_xor(m, off));
                float e0 = __expf(s0v - m), e1 = __expf(s1v - m);
                float sum = e0 + e1;
                #pragma unroll
                for (int off = 32; off; off >>= 1) sum += __shfl_xor(sum, off);
                float inv = 1.f / sum;
                pbuf[tid]      = e0 * inv;
                pbuf[64 + tid] = e1 * inv;
            }
            __syncthreads();
            if (tid < 32)
                stnc4(ws + WS_P + (size_t)(b*NH + h)*LL + tid*4,
                      *(float4*)(pbuf + tid*4));

            {   // ctx from V LDS: c = tid&63, lc = tid>>6 (16 slices of 8 l)
                int c = tid & 63, lc = tid >> 6;
                float a = 0.f;
                #pragma unroll
                for (int li = 0; li < 8; ++li) {
                    int l = lc*8 + li;
                    a += pbuf[l] * kvV[l*64 + c];
                }
                buf[lc*64 + c] = a;
            }
            __syncthreads();
            if (tid < 64) {
                float v = 0.f;
                #pragma unroll
                for (int lc = 0; lc < 16; ++lc) v += buf[lc*64 + tid];
                ctxv[tid] = v;
            }
            __syncthreads();
            if (tid < 16)
                stnc4(ws + WS_CTXB + (size_t)b*HH + h*64 + tid*4,
                      *(float4*)(ctxv + tid*4));
        }
        ++bno; gridbar(ws, bno);

        // ================= P2: GRU gates + finalize (blocks 0..31) =======
        if (blk < 32) {
            int cb = blk;
            int bb = cb >> 1, l0 = (cb & 1) * 64;

            if (tid < 128) {   // P slices for sc output -> scr[2048..2559]
                int hq = tid >> 4, li = (tid & 15) * 4;
                float4 pv = ldnc4(ws + WS_P + (size_t)(bb*NH + hq)*LL + l0 + li);
                *(float4*)(scr + 2048 + hq*64 + li) = pv;
            }
            {   // ctx [b][k] -> hs_s [k][16]
                int bx = tid & 15, kq = tid >> 4;     // k = kq*8 .. +7
                float4 v0, v1;
                ldnc4x2(ws + WS_CTXB + (size_t)bx*HH + kq*8,
                        ws + WS_CTXB + (size_t)bx*HH + kq*8 + 4, v0, v1);
                hs_s[(kq*8+0)*16 + bx] = v0.x; hs_s[(kq*8+1)*16 + bx] = v0.y;
                hs_s[(kq*8+2)*16 + bx] = v0.z; hs_s[(kq*8+3)*16 + bx] = v0.w;
                hs_s[(kq*8+4)*16 + bx] = v1.x; hs_s[(kq*8+5)*16 + bx] = v1.y;
                hs_s[(kq*8+6)*16 + bx] = v1.z; hs_s[(kq*8+7)*16 + bx] = v1.w;
            }
            __syncthreads();
            if (tid < 64) {   // sc output
                float s = 0.f;
                #pragma unroll
                for (int hq = 0; hq < NH; ++hq) s += scr[2048 + hq*64 + tid];
                float v = (t < olen[bb]) ? s*0.125f : 0.f;
                __builtin_nontemporal_store(v,
                    out + OUT_SC_OFF + ((size_t)t*BB + bb)*LL + l0 + tid);
            }
            __syncthreads();

            int c4 = tid & 3, b4 = (tid >> 2) & 3, kc = tid >> 4;
            int wv = tid >> 6;
            float4 xv[8];
            #pragma unroll
            for (int i = 0; i < 8; ++i)
                xv[i] = *(const float4*)(hs_s + (kc + 64*i)*16 + b4*4);
            float vg[6];

            #define GATE(gslot, WMAT, GG) { \
                const float* wp = WMAT + (size_t)kc*(3*HH) + (GG)*HH + cb*16 + c4*4; \
                float a00=0,a01=0,a02=0,a03=0, a10=0,a11=0,a12=0,a13=0; \
                float a20=0,a21=0,a22=0,a23=0, a30=0,a31=0,a32=0,a33=0; \
                _Pragma("unroll") \
                for (int i = 0; i < 8; ++i) { \
                    float4 w4 = *(const float4*)wp; wp += (size_t)64*(3*HH); \
                    float4 x4 = xv[i]; \
                    a00 += x4.x*w4.x; a01 += x4.x*w4.y; a02 += x4.x*w4.z; a03 += x4.x*w4.w; \
                    a10 += x4.y*w4.x; a11 += x4.y*w4.y; a12 += x4.y*w4.z; a13 += x4.y*w4.w; \
                    a20 += x4.z*w4.x; a21 += x4.z*w4.y; a22 += x4.z*w4.z; a23 += x4.z*w4.w; \
                    a30 += x4.w*w4.x; a31 += x4.w*w4.y; a32 += x4.w*w4.z; a33 += x4.w*w4.w; \
                } \
                float acc2[4][4] = {{a00,a01,a02,a03},{a10,a11,a12,a13}, \
                                    {a20,a21,a22,a23},{a30,a31,a32,a33}}; \
                _Pragma("unroll") \
                for (int bi = 0; bi < 4; ++bi) \
                    _Pragma("unroll") \
                    for (int ci = 0; ci < 4; ++ci) { \
                        float vz = acc2[bi][ci]; \
                        vz += __shfl_xor(vz, 16); \
                        vz += __shfl_xor(vz, 32); \
                        acc2[bi][ci] = vz; \
                    } \
                if ((tid & 48) == 0) { \
                    _Pragma("unroll") \
                    for (int bi = 0; bi < 4; ++bi) \
                        *(float4*)(scr + wv*256 + (b4*4+bi)*16 + c4*4) = \
                            make_float4(acc2[bi][0], acc2[bi][1], acc2[bi][2], acc2[bi][3]); \
                } \
                __syncthreads(); \
                float sred = 0.f; \
                if (tid < 256) { \
                    _Pragma("unroll") \
                    for (int w = 0; w < 16; ++w) sred += scr[w*256 + tid]; \
                } \
                vg[gslot] = sred; \
                __syncthreads(); }

            GATE(0, Wih, 0) GATE(1, Wih, 1) GATE(2, Wih, 2)

            {   // restage hs_s with h_prev [k][b]
                float4 v0, v1;
                ldnc4x2(hs_prev + (size_t)tid*4, hs_prev + (size_t)(tid+1024)*4, v0, v1);
                *(float4*)(hs_s + tid*4) = v0;
                *(float4*)(hs_s + (tid+1024)*4) = v1;
            }
            __syncthreads();
            #pragma unroll
            for (int i = 0; i < 8; ++i)
                xv[i] = *(const float4*)(hs_s + (kc + 64*i)*16 + b4*4);

            GATE(3, Whh, 0) GATE(4, Whh, 1) GATE(5, Whh, 2)
            #undef GATE

            if (tid < 256) {   // finalize
                int bx = tid >> 4, c = tid & 15;
                int col = cb*16 + c;
                float gir = vg[0] + bih[col];
                float giz = vg[1] + bih[HH + col];
                float gin = vg[2] + bih[2*HH + col];
                float ghr = vg[3] + bhh[col];
                float ghz = vg[4] + bhh[HH + col];
                float ghn = vg[5] + bhh[2*HH + col];
                float r = 1.f/(1.f + __expf(-(gir + ghr)));
                float z = 1.f/(1.f + __expf(-(giz + ghz)));
                float xn = gin + r*ghn;
                float n = 1.f - 2.f/(__expf(2.f*xn) + 1.f);
                float hprev = hs_s[col*16 + bx];
                float hnew = (1.f - z)*n + z*hprev;
                stnc1(hs_new + col*16 + bx, hnew);
                stnc1(hbk_new + (size_t)bx*HH + col, hnew);
                float hv = (t < olen[bx]) ? hnew : 0.f;
                __builtin_nontemporal_store(hv,
                    out + OUT_HID_OFF + ((size_t)t*BB + bx)*HH + col);
            }
        }
        ++bno; gridbar(ws, bno);

        // ================= P3: logits + per-block argmax (all 250) =======
        {
            {   // stage h_new [k][b] -> hs_s
                float4 v0, v1;
                ldnc4x2(hs_new + (size_t)tid*4, hs_new + (size_t)(tid+1024)*4, v0, v1);
                *(float4*)(hs_s + tid*4) = v0;
                *(float4*)(hs_s + (tid+1024)*4) = v1;
            }
            __syncthreads();

            int c4 = tid & 3, bq4 = (tid >> 2) & 3, kc = tid >> 4;
            int wv = tid >> 6;
            u64 vmax = 0ull;

            #pragma unroll
            for (int p = 0; p < 4; ++p) {
                float a00=0,a01=0,a02=0,a03=0, a10=0,a11=0,a12=0,a13=0;
                float a20=0,a21=0,a22=0,a23=0, a30=0,a31=0,a32=0,a33=0;
                bool useLds = classA ? (p == 0) : (p < 3);
                #pragma unroll
                for (int i = 0; i < 8; ++i) {   // k = kc + 64*i
                    int k = kc + 64*i;
                    float4 w4;
                    if (useLds) w4 = *(const float4*)(wf + ((classA ? 0 : p)*512 + k)*16 + c4*4);
                    else        w4 = *(const float4*)(Wf + (size_t)k*VV + colbase + p*16 + c4*4);
                    float4 h4 = *(const float4*)(hs_s + k*16 + bq4*4);
                    a00 += h4.x*w4.x; a01 += h4.x*w4.y; a02 += h4.x*w4.z; a03 += h4.x*w4.w;
                    a10 += h4.y*w4.x; a11 += h4.y*w4.y; a12 += h4.y*w4.z; a13 += h4.y*w4.w;
                    a20 += h4.z*w4.x; a21 += h4.z*w4.y; a22 += h4.z*w4.z; a23 += h4.z*w4.w;
                    a30 += h4.w*w4.x; a31 += h4.w*w4.y; a32 += h4.w*w4.z; a33 += h4.w*w4.w;
                }
                float acc2[4][4] = {{a00,a01,a02,a03},{a10,a11,a12,a13},
                                    {a20,a21,a22,a23},{a30,a31,a32,a33}};
                #pragma unroll
                for (int bi = 0; bi < 4; ++bi)
                    #pragma unroll
                    for (int ci = 0; ci < 4; ++ci) {
                        float vz = acc2[bi][ci];
                        vz += __shfl_xor(vz, 16);
                        vz += __shfl_xor(vz, 32);
                        acc2[bi][ci] = vz;
                    }
                if ((tid & 48) == 0) {
                    #pragma unroll
                    for (int bi = 0; bi < 4; ++bi)
                        *(float4*)(scr + wv*256 + (bq4*4+bi)*16 + c4*4) =
                            make_float4(acc2[bi][0], acc2[bi][1], acc2[bi][2], acc2[bi][3]);
                }
                __syncthreads();
                if (tid < 256) {
                    int bx = tid >> 4, c = tid & 15;
                    int col = colbase + p*16 + c;
                    float s = bf[col];
                    #pragma unroll
                    for (int w = 0; w < 16; ++w) s += scr[w*256 + tid];
                    bool active = t < olen[bx];
                    __builtin_nontemporal_store(active ? s : 0.f,
                        out + ((size_t)t*BB + bx)*VV + col);
                    unsigned u = __float_as_uint(s);
                    u = (u & 0x80000000u) ? ~u : (u | 0x80000000u);
                    u64 e = ((u64)u << 32) | (u64)(0xFFFFFFFFu - (unsigned)col);
                    #pragma unroll
                    for (int off = 1; off < 16; off <<= 1)
                        e = u64max(e, (u64)__shfl_xor((long long)e, off));
                    if ((tid & 15) == 0) vmax = u64max(vmax, e);
                }
                __syncthreads();
            }
            if (tid < 256 && (tid & 15) == 0)
                __hip_atomic_store(&cand[blk*BB + (tid >> 4)], vmax,
                                   __ATOMIC_RELAXED, __HIP_MEMORY_SCOPE_AGENT);
        }
        if (t < TT - 1) { ++bno; gridbar(ws, bno); }
    }
}

extern "C" void kernel_launch(void* const* d_in, const int* in_sizes, int n_in,
                              void* d_out, int out_size, void* d_ws, size_t ws_size,
                              hipStream_t stream) {
    const float* mem = (const float*)d_in[0];
    const float* emb = (const float*)d_in[1];
    const float* Wq  = (const float*)d_in[2];
    const float* bq  = (const float*)d_in[3];
    const float* Wk  = (const float*)d_in[4];
    const float* bk  = (const float*)d_in[5];
    const float* Wv  = (const float*)d_in[6];
    const float* bv  = (const float*)d_in[7];
    const float* Wih = (const float*)d_in[8];
    const float* bih = (const float*)d_in[9];
    const float* Whh = (const float*)d_in[10];
    const float* bhh = (const float*)d_in[11];
    const float* Wf  = (const float*)d_in[12];
    const float* bf  = (const float*)d_in[13];
    const int* olen  = (const int*)d_in[14];
    float* out = (float*)d_out;
    float* ws  = (float*)d_ws;

    hipLaunchKernelGGL(kv_kernel, dim3(2048), dim3(256), 0, stream,
                       mem, Wk, bk, Wv, bv, ws);
    hipLaunchKernelGGL(mega_kernel, dim3(NBLK), dim3(NTHR), 0, stream,
                       emb, Wq, bq, Wih, bih, Whh, bhh, Wf, bf, olen, ws, out);
}

// Round 14
// 1427.507 us; speedup vs baseline: 1.9746x; 1.9746x over previous
//
#include <hip/hip_runtime.h>

#define LL 128      // memory length
#define BB 16       // batch
#define HH 512      // hidden
#define VV 16000    // vocab
#define TT 32       // steps
#define NH 8        // heads
#define DK 64       // head dim

// workspace layout (float offsets)
#define WS_K 0
#define WS_V (LL*BB*HH)
#define WS_HID0 (2*LL*BB*HH)
#define WS_HID1 (WS_HID0 + BB*HH)
#define WS_CTX  (WS_HID1 + BB*HH)
#define WS_P    (WS_CTX + BB*HH)          // p[b][h][128]
#define WS_HS   (WS_P + BB*NH*LL)         // h_new in [k][b] layout (512*16)
#define WS_SLOTS_F (WS_HS + 6*BB*HH)      // uint64 argmax slots (8B aligned)
#define WS_WFP (WS_SLOTS_F + 2*(TT+1)*BB + 16)  // packed Wf tiles [500][512][32]

#define OUT_HID_OFF ((size_t)TT*BB*VV)
#define OUT_SC_OFF  (OUT_HID_OFF + (size_t)TT*BB*HH)

// slots[t*BB+b]: hi32 = monotonic float encoding, lo32 = 0xFFFFFFFF - col
// atomicMax -> max value, tie -> smallest col (jnp.argmax first occurrence)

// K|V projection + Wf pack: grid 2548.
//  blocks <2048: 128 rowgroups(16 rows) x 16 coltiles (K|V), padded-LDS GEMM.
//  blocks >=2048: 500 pack blocks -> WS_WFP[m][k][32] contiguous tiles.
// Block 0 additionally does the per-call init (hid0 zero, argmax slots).
__global__ __launch_bounds__(256) void kv_kernel(const float* __restrict__ mem,
        const float* __restrict__ Wk, const float* __restrict__ bk,
        const float* __restrict__ Wv, const float* __restrict__ bv,
        const float* __restrict__ Wf, float* __restrict__ ws) {
    int blk = blockIdx.x;
    int tid = threadIdx.x;

    if (blk >= 2048) {          // ---- Wf pack: m = blk-2048, cols [m*32, +32)
        int m = blk - 2048;
        int colb = m * 32;
        float* dst = ws + WS_WFP + (size_t)m*16384;
        #pragma unroll
        for (int j = 0; j < 16; ++j) {
            int i = tid + 256*j;            // 4096 float4
            int k = i >> 3, c4 = i & 7;
            float4 v = *(const float4*)(Wf + (size_t)k*VV + colb + c4*4);
            *(float4*)(dst + (size_t)k*32 + c4*4) = v;
        }
        return;
    }

    int rg = blk >> 4, ct = blk & 15;
    int isV = ct >= 8;
    int colbase = (ct & 7) * 64;
    const float* W = isV ? Wv : Wk;
    const float* bias = isV ? bv : bk;
    float* outp = ws + (isV ? WS_V : WS_K);
    int rowbase = rg * 16;
    __shared__ float As[16*516];

    {   // stage 16x512 A rows into padded LDS
        const float4* srcp = (const float4*)(mem + (size_t)rowbase*512);
        #pragma unroll
        for (int j = 0; j < 8; ++j) {
            int i = tid + 256*j;
            float4 v = srcp[i];
            int row = i >> 7, c4i = i & 127;
            *(float4*)(As + row*516 + c4i*4) = v;
        }
    }
    if (blk == 0) {
        for (int i = tid; i < BB*HH; i += 256) ws[WS_HID0 + i] = 0.f;
        unsigned long long* slots = (unsigned long long*)(ws + WS_SLOTS_F);
        for (int i = tid; i < (TT+1)*BB; i += 256)
            slots[i] = (i < BB) ? 0xFFFFFFFFull : 0ull;   // step0 argmax(zeros)=0
    }
    __syncthreads();

    int cq = tid & 15;
    int rq4 = (tid >> 4) & 3;
    int kq = tid >> 6;                      // 0..3: k-quarter (128 k each)
    float acc[4][4];
    #pragma unroll
    for (int i = 0; i < 4; ++i) { acc[i][0]=0.f; acc[i][1]=0.f; acc[i][2]=0.f; acc[i][3]=0.f; }
    const float* wp = W + colbase + cq*4;
    for (int k4 = kq*32; k4 < kq*32 + 32; ++k4) {
        float4 a0 = *(const float4*)(As + (rq4*4+0)*516 + k4*4);
        float4 a1 = *(const float4*)(As + (rq4*4+1)*516 + k4*4);
        float4 a2 = *(const float4*)(As + (rq4*4+2)*516 + k4*4);
        float4 a3 = *(const float4*)(As + (rq4*4+3)*516 + k4*4);
        const float* wrow = wp + (size_t)(4*k4)*512;
        float4 w0 = *(const float4*)(wrow);
        float4 w1 = *(const float4*)(wrow + 512);
        float4 w2 = *(const float4*)(wrow + 1024);
        float4 w3 = *(const float4*)(wrow + 1536);
        #define KV_FMA(ri, A) \
            acc[ri][0] += A.x*w0.x + A.y*w1.x + A.z*w2.x + A.w*w3.x; \
            acc[ri][1] += A.x*w0.y + A.y*w1.y + A.z*w2.y + A.w*w3.y; \
            acc[ri][2] += A.x*w0.z + A.y*w1.z + A.z*w2.z + A.w*w3.z; \
            acc[ri][3] += A.x*w0.w + A.y*w1.w + A.z*w2.w + A.w*w3.w;
        KV_FMA(0, a0) KV_FMA(1, a1) KV_FMA(2, a2) KV_FMA(3, a3)
        #undef KV_FMA
    }
    __syncthreads();
    float* red = As;
    #pragma unroll
    for (int ri = 0; ri < 4; ++ri)
        *(float4*)(red + ri*1024 + tid*4) =
            make_float4(acc[ri][0], acc[ri][1], acc[ri][2], acc[ri][3]);
    __syncthreads();
    {
        int c4 = tid & 15, row = tid >> 4;
        int rq = row >> 2, ri = row & 3;
        float4 b4v = *(const float4*)(bias + colbase + c4*4);
        float o[4] = {b4v.x, b4v.y, b4v.z, b4v.w};
        #pragma unroll
        for (int kq2 = 0; kq2 < 4; ++kq2) {
            const float* pr = red + ri*1024 + (kq2*64 + rq*16 + c4)*4;
            o[0] += pr[0]; o[1] += pr[1]; o[2] += pr[2]; o[3] += pr[3];
        }
        *(float4*)(outp + (size_t)(rowbase + row)*512 + colbase + c4*4) =
            make_float4(o[0], o[1], o[2], o[3]);
    }
}

// Attention: 128 blocks = (b,h), 256 threads. qproj slice + scores + softmax + ctx.
__global__ __launch_bounds__(256) void attn_kernel(
        const float* __restrict__ emb, const float* __restrict__ Wq,
        const float* __restrict__ bq, float* __restrict__ ws, int t) {
    int b = blockIdx.x >> 3, h = blockIdx.x & 7;
    int tid = threadIdx.x;
    const float* hid = ws + ((t & 1) ? WS_HID1 : WS_HID0);
    unsigned long long* slots = (unsigned long long*)(ws + WS_SLOTS_F);
    __shared__ float q[2*HH];
    __shared__ float part[8*64];
    __shared__ float qh[64];
    __shared__ float sp[2*LL];
    __shared__ float p[LL];
    __shared__ float cpart[4*64];

    unsigned long long slot = slots[t*BB + b];
    unsigned idx = 0xFFFFFFFFu - (unsigned)(slot & 0xFFFFFFFFull);
    for (int i = tid; i < HH; i += 256) {
        q[i] = emb[(size_t)idx*HH + i];
        q[HH + i] = hid[b*HH + i];
    }
    __syncthreads();

    {   // qproj: thread = (c2 0..31 two cols, kc 0..7 k-slices of 128)
        int c2 = tid & 31, kc = tid >> 5;
        const float* wp = Wq + (size_t)(kc*128)*HH + h*64 + c2*2;
        const float* qp = q + kc*128;
        float a0 = 0.f, a1 = 0.f;
        #pragma unroll 8
        for (int kk = 0; kk < 128; ++kk) {
            float x = qp[kk];
            float2 w2 = *(const float2*)(wp + (size_t)kk*HH);
            a0 += x*w2.x; a1 += x*w2.y;
        }
        part[kc*64 + c2*2]     = a0;
        part[kc*64 + c2*2 + 1] = a1;
    }
    __syncthreads();
    if (tid < 64) {
        float s = bq[h*64 + tid];
        #pragma unroll
        for (int kc = 0; kc < 8; ++kc) s += part[kc*64 + tid];
        qh[tid] = s;
    }
    __syncthreads();

    {   // scores: thread = (l 0..127, jh 0..1)
        int l = tid & 127, jh = tid >> 7;
        const float4* kr = (const float4*)(ws + WS_K + ((size_t)(l*BB + b))*HH + h*DK) + jh*8;
        const float4* q4 = (const float4*)qh + jh*8;
        float acc = 0.f;
        #pragma unroll
        for (int j = 0; j < 8; ++j) {
            float4 kv = kr[j], qq = q4[j];
            acc += qq.x*kv.x + qq.y*kv.y + qq.z*kv.z + qq.w*kv.w;
        }
        sp[jh*128 + l] = acc;
    }
    __syncthreads();

    if (tid < 64) {   // softmax over 128 by wave 0
        float s0 = (sp[tid]      + sp[128 + tid]) * 0.125f;
        float s1 = (sp[64 + tid] + sp[192 + tid]) * 0.125f;
        float m = fmaxf(s0, s1);
        #pragma unroll
        for (int off = 32; off; off >>= 1) m = fmaxf(m, __shfl_xor(m, off));
        float e0 = expf(s0 - m), e1 = expf(s1 - m);
        float sum = e0 + e1;
        #pragma unroll
        for (int off = 32; off; off >>= 1) sum += __shfl_xor(sum, off);
        float inv = 1.f / sum;
        p[tid]      = e0 * inv;
        p[64 + tid] = e1 * inv;
    }
    __syncthreads();
    if (tid < 128) ws[WS_P + (size_t)(b*NH + h)*LL + tid] = p[tid];

    {   // ctx: thread = (c 0..63, lc 0..3 l-slices of 32)
        int c = tid & 63, lc = tid >> 6;
        const float* Vp = ws + WS_V + h*DK + c;
        float acc = 0.f;
        #pragma unroll 8
        for (int li = 0; li < 32; ++li) {
            int l = lc*32 + li;
            acc += p[l] * Vp[(size_t)(l*BB + b)*HH];
        }
        cpart[lc*64 + c] = acc;
    }
    __syncthreads();
    if (tid < 64)
        ws[WS_CTX + b*HH + h*DK + tid] =
            cpart[tid] + cpart[64+tid] + cpart[128+tid] + cpart[192+tid];
}

// GRU gates + finalize: 32 blocks x 512 thr. Block cb owns cols cb*16..+16 for
// ALL 6 gate-matrices -> block-local finalize. Also writes sc + hiddens outputs,
// h_new carry (ping-pong) and the [k][b] h-copy for logits.
__global__ __launch_bounds__(512) void gates_kernel(
        const float* __restrict__ Wih, const float* __restrict__ bih,
        const float* __restrict__ Whh, const float* __restrict__ bhh,
        const int* __restrict__ olen, float* __restrict__ ws,
        float* __restrict__ out, int t) {
    int cb = blockIdx.x;      // 0..31
    int tid = threadIdx.x;
    const float* hid_in = ws + ((t & 1) ? WS_HID1 : WS_HID0);
    float* hid_out = ws + ((t & 1) ? WS_HID0 : WS_HID1);
    const float* ctx = ws + WS_CTX;
    __shared__ float xs[512*20];      // ctx  [k][b] stride 20
    __shared__ float hh[512*20];      // hid  [k][b] stride 20
    __shared__ float part[8*256];
    __shared__ float gacc[6*256];

    for (int i = tid; i < BB*HH; i += 512) {
        int bb = i >> 9, k = i & 511;
        xs[k*20 + bb] = ctx[i];
        hh[k*20 + bb] = hid_in[i];
    }
    if (tid < 64) {   // sc output: 64 of 2048 (b,l) pairs per block
        int e = cb*64 + tid;
        int b = e >> 7, l = e & 127;
        float s = 0.f;
        #pragma unroll
        for (int hq = 0; hq < NH; ++hq)
            s += ws[WS_P + (size_t)(b*NH + hq)*LL + l];
        out[OUT_SC_OFF + ((size_t)t*BB + b)*LL + l] = (t < olen[b]) ? s*0.125f : 0.f;
    }
    __syncthreads();

    int c4 = tid & 3, b4 = (tid >> 2) & 3, kc = tid >> 4;  // 4 x 4 x 32
    int wv = tid >> 6;
    for (int g = 0; g < 6; ++g) {
        const float* W = (g < 3) ? Wih : Whh;
        int gg = (g < 3) ? g : g - 3;
        const float* xsrc = (g < 3) ? xs : hh;
        const float* wp = W + (size_t)kc*(3*HH) + gg*HH + cb*16 + c4*4;
        const float* xp = xsrc + kc*20 + b4*4;
        float acc[4][4];
        #pragma unroll
        for (int i = 0; i < 4; ++i) { acc[i][0]=0.f; acc[i][1]=0.f; acc[i][2]=0.f; acc[i][3]=0.f; }
        #pragma unroll 8
        for (int i = 0; i < 16; ++i) {     // k = kc + 32*i
            float4 w4 = *(const float4*)wp;
            float4 x4 = *(const float4*)xp;
            wp += (size_t)32*(3*HH);
            xp += 32*20;
            acc[0][0] += x4.x*w4.x; acc[0][1] += x4.x*w4.y; acc[0][2] += x4.x*w4.z; acc[0][3] += x4.x*w4.w;
            acc[1][0] += x4.y*w4.x; acc[1][1] += x4.y*w4.y; acc[1][2] += x4.y*w4.z; acc[1][3] += x4.y*w4.w;
            acc[2][0] += x4.z*w4.x; acc[2][1] += x4.z*w4.y; acc[2][2] += x4.z*w4.z; acc[2][3] += x4.z*w4.w;
            acc[3][0] += x4.w*w4.x; acc[3][1] += x4.w*w4.y; acc[3][2] += x4.w*w4.z; acc[3][3] += x4.w*w4.w;
        }
        #pragma unroll
        for (int bi = 0; bi < 4; ++bi)
            #pragma unroll
            for (int ci = 0; ci < 4; ++ci) {
                float v = acc[bi][ci];
                v += __shfl_xor(v, 16);
                v += __shfl_xor(v, 32);
                acc[bi][ci] = v;
            }
        if ((tid & 48) == 0) {   // lanes 0..15 of each wave hold (c4,b4) partial
            #pragma unroll
            for (int bi = 0; bi < 4; ++bi)
                *(float4*)(part + wv*256 + (b4*4+bi)*16 + c4*4) =
                    make_float4(acc[bi][0], acc[bi][1], acc[bi][2], acc[bi][3]);
        }
        __syncthreads();
        if (tid < 256) {
            int b = tid >> 4, c = tid & 15;
            float s = 0.f;
            #pragma unroll
            for (int w = 0; w < 8; ++w) s += part[w*256 + b*16 + c];
            gacc[g*256 + b*16 + c] = s;
        }
        __syncthreads();
    }

    // finalize: 256 threads, one (b, c) each
    if (tid < 256) {
        int b = tid >> 4, c = tid & 15;
        int col = cb*16 + c;
        float gir = gacc[0*256 + b*16 + c] + bih[col];
        float giz = gacc[1*256 + b*16 + c] + bih[HH + col];
        float gin = gacc[2*256 + b*16 + c] + bih[2*HH + col];
        float ghr = gacc[3*256 + b*16 + c] + bhh[col];
        float ghz = gacc[4*256 + b*16 + c] + bhh[HH + col];
        float ghn = gacc[5*256 + b*16 + c] + bhh[2*HH + col];
        float r = 1.f/(1.f + __expf(-(gir + ghr)));
        float z = 1.f/(1.f + __expf(-(giz + ghz)));
        float xn = gin + r*ghn;
        float n = 1.f - 2.f/(__expf(2.f*xn) + 1.f);
        float hprev = hh[col*20 + b];
        float hnew = (1.f - z)*n + z*hprev;
        hid_out[b*HH + col] = hnew;                                    // carry (unmasked)
        out[OUT_HID_OFF + ((size_t)t*BB + b)*HH + col] = (t < olen[b]) ? hnew : 0.f;
        ws[WS_HS + col*16 + b] = hnew;                                 // [k][b] for logits
    }
}

// Logits (pure GEMM, packed Wf tiles) + fused argmax. 500 blocks x 256 thr,
// 32 cols/block. Thread = (c4: tid&7 col-quads, kc: tid>>3 k-slices);
// k = kc + 32*i (interleaved for LDS bank spread). Wf tile is L2-resident.
__global__ __launch_bounds__(256) void logits_kernel(
        const float* __restrict__ bf, const int* __restrict__ olen,
        float* __restrict__ ws, float* __restrict__ out, int t) {
    __shared__ float hs[HH*20];              // h_new [k][b], stride 20
    __shared__ float red[4*512];             // per-wave partials [w][b*32+c]
    __shared__ unsigned long long am[BB*16];
    int tid = threadIdx.x;

    {   // stage h from ws [512][16] -> padded LDS
        const float4* s4 = (const float4*)(ws + WS_HS);
        #pragma unroll
        for (int j = 0; j < 8; ++j) {
            int i = tid + 256*j;             // 2048 float4
            float4 v = s4[i];
            int row = i >> 2, qo = i & 3;
            *(float4*)(hs + row*20 + qo*4) = v;
        }
    }
    __syncthreads();

    int c4 = tid & 7, kc = tid >> 3;         // 8 col-quads, 32 k-slices
    int colbase = blockIdx.x * 32;
    const float* wtile = ws + WS_WFP + (size_t)blockIdx.x*16384;
    float acc[16][4];
    #pragma unroll
    for (int bi = 0; bi < 16; ++bi) { acc[bi][0]=0.f; acc[bi][1]=0.f; acc[bi][2]=0.f; acc[bi][3]=0.f; }
    const float* wp = wtile + (size_t)kc*32 + c4*4;
    const float* hp = hs + kc*20;
    #pragma unroll 8
    for (int i = 0; i < 16; ++i) {           // k = kc + 32*i
        float4 w4 = *(const float4*)wp;
        float4 h0 = *(const float4*)(hp);
        float4 h1 = *(const float4*)(hp + 4);
        float4 h2 = *(const float4*)(hp + 8);
        float4 h3 = *(const float4*)(hp + 12);
        wp += 32 * 32;
        hp += 32 * 20;
        #define LACC(bi, hv) acc[bi][0] += (hv)*w4.x; acc[bi][1] += (hv)*w4.y; \
                             acc[bi][2] += (hv)*w4.z; acc[bi][3] += (hv)*w4.w;
        LACC(0,h0.x)  LACC(1,h0.y)  LACC(2,h0.z)  LACC(3,h0.w)
        LACC(4,h1.x)  LACC(5,h1.y)  LACC(6,h1.z)  LACC(7,h1.w)
        LACC(8,h2.x)  LACC(9,h2.y)  LACC(10,h2.z) LACC(11,h2.w)
        LACC(12,h3.x) LACC(13,h3.y) LACC(14,h3.z) LACC(15,h3.w)
        #undef LACC
    }

    // reduce over kc: in-wave lane bits 3,4,5
    #pragma unroll
    for (int bi = 0; bi < 16; ++bi)
        #pragma unroll
        for (int ci = 0; ci < 4; ++ci) {
            float v = acc[bi][ci];
            v += __shfl_xor(v, 8);
            v += __shfl_xor(v, 16);
            v += __shfl_xor(v, 32);
            acc[bi][ci] = v;
        }
    int wv = tid >> 6;
    if ((tid & 56) == 0) {   // lanes 0..7 (= c4) of each wave
        #pragma unroll
        for (int bi = 0; bi < 16; ++bi)
            *(float4*)(red + wv*512 + bi*32 + c4*4) =
                make_float4(acc[bi][0], acc[bi][1], acc[bi][2], acc[bi][3]);
    }
    __syncthreads();

    // final: 512 outputs (16b x 32c), 2 per thread
    {
        int b = tid >> 4, cp = (tid & 15) * 2;
        float2 bf2 = *(const float2*)(bf + colbase + cp);
        float v0 = bf2.x, v1 = bf2.y;
        #pragma unroll
        for (int w = 0; w < 4; ++w) {
            v0 += red[w*512 + b*32 + cp];
            v1 += red[w*512 + b*32 + cp + 1];
        }
        bool active = t < olen[b];
        float2 ov; ov.x = active ? v0 : 0.f; ov.y = active ? v1 : 0.f;
        *(float2*)(out + ((size_t)t*BB + b)*VV + colbase + cp) = ov;

        unsigned u0 = __float_as_uint(v0);
        u0 = (u0 & 0x80000000u) ? ~u0 : (u0 | 0x80000000u);
        unsigned u1 = __float_as_uint(v1);
        u1 = (u1 & 0x80000000u) ? ~u1 : (u1 | 0x80000000u);
        unsigned long long e0 = ((unsigned long long)u0 << 32)
                              | (unsigned long long)(0xFFFFFFFFu - (unsigned)(colbase + cp));
        unsigned long long e1 = ((unsigned long long)u1 << 32)
                              | (unsigned long long)(0xFFFFFFFFu - (unsigned)(colbase + cp + 1));
        am[b*16 + (tid & 15)] = e0 > e1 ? e0 : e1;
    }
    __syncthreads();
    if (tid < BB) {
        unsigned long long m = 0ull;
        #pragma unroll
        for (int i = 0; i < 16; ++i) {
            unsigned long long v = am[tid*16 + i];
            m = v > m ? v : m;
        }
        unsigned long long* slots = (unsigned long long*)(ws + WS_SLOTS_F);
        atomicMax(&slots[(size_t)(t+1)*BB + tid], m);
    }
}

extern "C" void kernel_launch(void* const* d_in, const int* in_sizes, int n_in,
                              void* d_out, int out_size, void* d_ws, size_t ws_size,
                              hipStream_t stream) {
    const float* mem = (const float*)d_in[0];
    const float* emb = (const float*)d_in[1];
    const float* Wq  = (const float*)d_in[2];
    const float* bq  = (const float*)d_in[3];
    const float* Wk  = (const float*)d_in[4];
    const float* bk  = (const float*)d_in[5];
    const float* Wv  = (const float*)d_in[6];
    const float* bv  = (const float*)d_in[7];
    const float* Wih = (const float*)d_in[8];
    const float* bih = (const float*)d_in[9];
    const float* Whh = (const float*)d_in[10];
    const float* bhh = (const float*)d_in[11];
    const float* Wf  = (const float*)d_in[12];
    const float* bf  = (const float*)d_in[13];
    const int* olen  = (const int*)d_in[14];
    float* out = (float*)d_out;
    float* ws  = (float*)d_ws;

    hipLaunchKernelGGL(kv_kernel, dim3(2548), dim3(256), 0, stream,
                       mem, Wk, bk, Wv, bv, Wf, ws);
    for (int t = 0; t < TT; ++t) {
        hipLaunchKernelGGL(attn_kernel, dim3(BB*NH), dim3(256), 0, stream, emb, Wq, bq, ws, t);
        hipLaunchKernelGGL(gates_kernel, dim3(32), dim3(512), 0, stream,
                           Wih, bih, Whh, bhh, olen, ws, out, t);
        hipLaunchKernelGGL(logits_kernel, dim3(500), dim3(256), 0, stream,
                           bf, olen, ws, out, t);
    }
}

// Round 16
// 1250.008 us; speedup vs baseline: 2.2549x; 1.1420x over previous
//
#include <hip/hip_runtime.h>

#define LL 128      // memory length
#define BB 16       // batch
#define HH 512      // hidden
#define VV 16000    // vocab
#define TT 32       // steps
#define NH 8        // heads
#define DK 64       // head dim

// workspace layout (float offsets)
#define WS_K 0
#define WS_V (LL*BB*HH)
#define WS_HID0 (2*LL*BB*HH)
#define WS_HID1 (WS_HID0 + BB*HH)
#define WS_CTX  (WS_HID1 + BB*HH)
#define WS_P    (WS_CTX + BB*HH)          // p[b][h][128]
#define WS_HS   (WS_P + BB*NH*LL)         // h_new in [k][b] layout (512*16)
#define WS_CAND (WS_HS + BB*HH + 16)      // u64 cand[512][16] (8B aligned)
#define WS_WFP  (WS_CAND + 2*512*BB)      // packed Wf tiles [500][512][32]

#define OUT_HID_OFF ((size_t)TT*BB*VV)
#define OUT_SC_OFF  (OUT_HID_OFF + (size_t)TT*BB*HH)

typedef unsigned long long u64;
__device__ __forceinline__ u64 u64max(u64 a, u64 b) { return a > b ? a : b; }

// cand[m][b]: hi32 = monotonic float encoding, lo32 = 0xFFFFFFFF - col.
// max over m -> max logit, tie -> smallest col (jnp.argmax first occurrence).

// K|V projection + Wf pack: grid 2548.
__global__ __launch_bounds__(256) void kv_kernel(const float* __restrict__ mem,
        const float* __restrict__ Wk, const float* __restrict__ bk,
        const float* __restrict__ Wv, const float* __restrict__ bv,
        const float* __restrict__ Wf, float* __restrict__ ws) {
    int blk = blockIdx.x;
    int tid = threadIdx.x;

    if (blk >= 2048) {          // ---- Wf pack: m = blk-2048, cols [m*32, +32)
        int m = blk - 2048;
        int colb = m * 32;
        float* dst = ws + WS_WFP + (size_t)m*16384;
        #pragma unroll
        for (int j = 0; j < 16; ++j) {
            int i = tid + 256*j;            // 4096 float4
            int k = i >> 3, c4 = i & 7;
            float4 v = *(const float4*)(Wf + (size_t)k*VV + colb + c4*4);
            *(float4*)(dst + (size_t)k*32 + c4*4) = v;
        }
        return;
    }

    int rg = blk >> 4, ct = blk & 15;
    int isV = ct >= 8;
    int colbase = (ct & 7) * 64;
    const float* W = isV ? Wv : Wk;
    const float* bias = isV ? bv : bk;
    float* outp = ws + (isV ? WS_V : WS_K);
    int rowbase = rg * 16;
    __shared__ float As[16*516];

    {   // stage 16x512 A rows into padded LDS
        const float4* srcp = (const float4*)(mem + (size_t)rowbase*512);
        #pragma unroll
        for (int j = 0; j < 8; ++j) {
            int i = tid + 256*j;
            float4 v = srcp[i];
            int row = i >> 7, c4i = i & 127;
            *(float4*)(As + row*516 + c4i*4) = v;
        }
    }
    if (blk == 0) {
        for (int i = tid; i < BB*HH; i += 256) ws[WS_HID0 + i] = 0.f;
        u64* cand = (u64*)(ws + WS_CAND);
        for (int i = tid; i < 512*BB; i += 256) cand[i] = 0ull;
    }
    __syncthreads();

    int cq = tid & 15;
    int rq4 = (tid >> 4) & 3;
    int kq = tid >> 6;                      // 0..3: k-quarter (128 k each)
    float acc[4][4];
    #pragma unroll
    for (int i = 0; i < 4; ++i) { acc[i][0]=0.f; acc[i][1]=0.f; acc[i][2]=0.f; acc[i][3]=0.f; }
    const float* wp = W + colbase + cq*4;
    for (int k4 = kq*32; k4 < kq*32 + 32; ++k4) {
        float4 a0 = *(const float4*)(As + (rq4*4+0)*516 + k4*4);
        float4 a1 = *(const float4*)(As + (rq4*4+1)*516 + k4*4);
        float4 a2 = *(const float4*)(As + (rq4*4+2)*516 + k4*4);
        float4 a3 = *(const float4*)(As + (rq4*4+3)*516 + k4*4);
        const float* wrow = wp + (size_t)(4*k4)*512;
        float4 w0 = *(const float4*)(wrow);
        float4 w1 = *(const float4*)(wrow + 512);
        float4 w2 = *(const float4*)(wrow + 1024);
        float4 w3 = *(const float4*)(wrow + 1536);
        #define KV_FMA(ri, A) \
            acc[ri][0] += A.x*w0.x + A.y*w1.x + A.z*w2.x + A.w*w3.x; \
            acc[ri][1] += A.x*w0.y + A.y*w1.y + A.z*w2.y + A.w*w3.y; \
            acc[ri][2] += A.x*w0.z + A.y*w1.z + A.z*w2.z + A.w*w3.z; \
            acc[ri][3] += A.x*w0.w + A.y*w1.w + A.z*w2.w + A.w*w3.w;
        KV_FMA(0, a0) KV_FMA(1, a1) KV_FMA(2, a2) KV_FMA(3, a3)
        #undef KV_FMA
    }
    __syncthreads();
    float* red = As;
    #pragma unroll
    for (int ri = 0; ri < 4; ++ri)
        *(float4*)(red + ri*1024 + tid*4) =
            make_float4(acc[ri][0], acc[ri][1], acc[ri][2], acc[ri][3]);
    __syncthreads();
    {
        int c4 = tid & 15, row = tid >> 4;
        int rq = row >> 2, ri = row & 3;
        float4 b4v = *(const float4*)(bias + colbase + c4*4);
        float o[4] = {b4v.x, b4v.y, b4v.z, b4v.w};
        #pragma unroll
        for (int kq2 = 0; kq2 < 4; ++kq2) {
            const float* pr = red + ri*1024 + (kq2*64 + rq*16 + c4)*4;
            o[0] += pr[0]; o[1] += pr[1]; o[2] += pr[2]; o[3] += pr[3];
        }
        *(float4*)(outp + (size_t)(rowbase + row)*512 + colbase + c4*4) =
            make_float4(o[0], o[1], o[2], o[3]);
    }
}

// Attention: 128 blocks = (b,h), 256 threads. cand-resolve + qproj + scores
// + softmax + ctx.
__global__ __launch_bounds__(256) void attn_kernel(
        const float* __restrict__ emb, const float* __restrict__ Wq,
        const float* __restrict__ bq, float* __restrict__ ws, int t) {
    int b = blockIdx.x >> 3, h = blockIdx.x & 7;
    int tid = threadIdx.x;
    const float* hid = ws + ((t & 1) ? WS_HID1 : WS_HID0);
    __shared__ float q[2*HH];
    __shared__ float part[4*64];
    __shared__ float qh[64];
    __shared__ float sp[2*LL];
    __shared__ float p[LL];
    __shared__ float cpart[4*64];
    __shared__ unsigned idx_s;

    if (t > 0) {   // resolve argmax from 512 (padded) block candidates
        if (tid < 64) {
            const u64* cp = (const u64*)(ws + WS_CAND) + b;
            u64 m = 0ull;
            #pragma unroll
            for (int j = 0; j < 8; ++j)
                m = u64max(m, cp[(size_t)(tid + 64*j)*BB]);
            #pragma unroll
            for (int off = 32; off; off >>= 1)
                m = u64max(m, (u64)__shfl_xor((long long)m, off));
            if (tid == 0) idx_s = 0xFFFFFFFFu - (unsigned)(m & 0xFFFFFFFFull);
        }
    } else if (tid == 0) idx_s = 0u;
    __syncthreads();
    unsigned idx = idx_s;
    for (int i = tid; i < HH; i += 256) {
        q[i] = emb[(size_t)idx*HH + i];
        q[HH + i] = hid[b*HH + i];
    }
    __syncthreads();

    {   // qproj: c4 = tid&15 (4 cols), kc = tid>>4 (16 slices); k = kc + 16*i
        int c4 = tid & 15, kc = tid >> 4;
        const float* wp = Wq + (size_t)kc*HH + h*64 + c4*4;
        float ax=0.f, ay=0.f, az=0.f, aw=0.f;
        #pragma unroll 8
        for (int i = 0; i < 64; ++i) {
            float x = q[kc + 16*i];
            float4 w4 = *(const float4*)wp;
            wp += (size_t)16*HH;
            ax += x*w4.x; ay += x*w4.y; az += x*w4.z; aw += x*w4.w;
        }
        float v;
        v = ax; v += __shfl_xor(v,16); v += __shfl_xor(v,32); ax = v;
        v = ay; v += __shfl_xor(v,16); v += __shfl_xor(v,32); ay = v;
        v = az; v += __shfl_xor(v,16); v += __shfl_xor(v,32); az = v;
        v = aw; v += __shfl_xor(v,16); v += __shfl_xor(v,32); aw = v;
        int wv = tid >> 6;
        if ((tid & 48) == 0)
            *(float4*)(part + wv*64 + c4*4) = make_float4(ax, ay, az, aw);
    }
    __syncthreads();
    if (tid < 64) {
        float s = bq[h*64 + tid];
        #pragma unroll
        for (int wv = 0; wv < 4; ++wv) s += part[wv*64 + tid];
        qh[tid] = s;
    }
    __syncthreads();

    {   // scores: thread = (l 0..127, jh 0..1)
        int l = tid & 127, jh = tid >> 7;
        const float4* kr = (const float4*)(ws + WS_K + ((size_t)(l*BB + b))*HH + h*DK) + jh*8;
        const float4* q4 = (const float4*)qh + jh*8;
        float acc = 0.f;
        #pragma unroll
        for (int j = 0; j < 8; ++j) {
            float4 kv = kr[j], qq = q4[j];
            acc += qq.x*kv.x + qq.y*kv.y + qq.z*kv.z + qq.w*kv.w;
        }
        sp[jh*128 + l] = acc;
    }
    __syncthreads();

    if (tid < 64) {   // softmax over 128 by wave 0
        float s0 = (sp[tid]      + sp[128 + tid]) * 0.125f;
        float s1 = (sp[64 + tid] + sp[192 + tid]) * 0.125f;
        float m = fmaxf(s0, s1);
        #pragma unroll
        for (int off = 32; off; off >>= 1) m = fmaxf(m, __shfl_xor(m, off));
        float e0 = expf(s0 - m), e1 = expf(s1 - m);
        float sum = e0 + e1;
        #pragma unroll
        for (int off = 32; off; off >>= 1) sum += __shfl_xor(sum, off);
        float inv = 1.f / sum;
        p[tid]      = e0 * inv;
        p[64 + tid] = e1 * inv;
    }
    __syncthreads();
    if (tid < 128) ws[WS_P + (size_t)(b*NH + h)*LL + tid] = p[tid];

    {   // ctx: thread = (c 0..63, lc 0..3 l-slices of 32)
        int c = tid & 63, lc = tid >> 6;
        const float* Vp = ws + WS_V + h*DK + c;
        float acc = 0.f;
        #pragma unroll 8
        for (int li = 0; li < 32; ++li) {
            int l = lc*32 + li;
            acc += p[l] * Vp[(size_t)(l*BB + b)*HH];
        }
        cpart[lc*64 + c] = acc;
    }
    __syncthreads();
    if (tid < 64)
        ws[WS_CTX + b*HH + h*DK + tid] =
            cpart[tid] + cpart[64+tid] + cpart[128+tid] + cpart[192+tid];
}

// GRU gates + finalize: 32 blocks x 512 thr. Fused r/z/n per weight matrix.
__global__ __launch_bounds__(512) void gates_kernel(
        const float* __restrict__ Wih, const float* __restrict__ bih,
        const float* __restrict__ Whh, const float* __restrict__ bhh,
        const int* __restrict__ olen, float* __restrict__ ws,
        float* __restrict__ out, int t) {
    int cb = blockIdx.x;      // 0..31
    int tid = threadIdx.x;
    const float* hid_in = ws + ((t & 1) ? WS_HID1 : WS_HID0);
    float* hid_out = ws + ((t & 1) ? WS_HID0 : WS_HID1);
    const float* ctx = ws + WS_CTX;
    __shared__ float xs[512*20];      // ctx  [k][b] stride 20
    __shared__ float hh[512*20];      // hid  [k][b] stride 20
    __shared__ float part[3*8*256];   // [g][wave][b*16+c]
    __shared__ float gacc[6*256];

    for (int i = tid; i < BB*HH; i += 512) {
        int bb = i >> 9, k = i & 511;
        xs[k*20 + bb] = ctx[i];
        hh[k*20 + bb] = hid_in[i];
    }
    if (tid < 64) {   // sc output: 64 of 2048 (b,l) pairs per block
        int e = cb*64 + tid;
        int b = e >> 7, l = e & 127;
        float s = 0.f;
        #pragma unroll
        for (int hq = 0; hq < NH; ++hq)
            s += ws[WS_P + (size_t)(b*NH + hq)*LL + l];
        out[OUT_SC_OFF + ((size_t)t*BB + b)*LL + l] = (t < olen[b]) ? s*0.125f : 0.f;
    }
    __syncthreads();

    int c4 = tid & 3, b4 = (tid >> 2) & 3, kc = tid >> 4;  // 4 x 4 x 32
    int wv = tid >> 6;
    #pragma unroll
    for (int pass = 0; pass < 2; ++pass) {
        const float* W = pass ? Whh : Wih;
        const float* xsrc = pass ? hh : xs;
        float aR[4][4], aZ[4][4], aN[4][4];
        #pragma unroll
        for (int i = 0; i < 4; ++i)
            #pragma unroll
            for (int j = 0; j < 4; ++j) { aR[i][j]=0.f; aZ[i][j]=0.f; aN[i][j]=0.f; }
        const float* wp = W + (size_t)kc*(3*HH) + cb*16 + c4*4;
        const float* xp = xsrc + kc*20 + b4*4;
        #pragma unroll 4
        for (int i = 0; i < 16; ++i) {     // k = kc + 32*i
            float4 wr = *(const float4*)(wp);
            float4 wz = *(const float4*)(wp + HH);
            float4 wn = *(const float4*)(wp + 2*HH);
            float4 x4 = *(const float4*)xp;
            wp += (size_t)32*(3*HH);
            xp += 32*20;
            #define GR(bi, xv) \
                aR[bi][0] += xv*wr.x; aR[bi][1] += xv*wr.y; aR[bi][2] += xv*wr.z; aR[bi][3] += xv*wr.w; \
                aZ[bi][0] += xv*wz.x; aZ[bi][1] += xv*wz.y; aZ[bi][2] += xv*wz.z; aZ[bi][3] += xv*wz.w; \
                aN[bi][0] += xv*wn.x; aN[bi][1] += xv*wn.y; aN[bi][2] += xv*wn.z; aN[bi][3] += xv*wn.w;
            GR(0, x4.x) GR(1, x4.y) GR(2, x4.z) GR(3, x4.w)
            #undef GR
        }
        #pragma unroll
        for (int bi = 0; bi < 4; ++bi)
            #pragma unroll
            for (int ci = 0; ci < 4; ++ci) {
                float v;
                v = aR[bi][ci]; v += __shfl_xor(v,16); v += __shfl_xor(v,32); aR[bi][ci] = v;
                v = aZ[bi][ci]; v += __shfl_xor(v,16); v += __shfl_xor(v,32); aZ[bi][ci] = v;
                v = aN[bi][ci]; v += __shfl_xor(v,16); v += __shfl_xor(v,32); aN[bi][ci] = v;
            }
        if ((tid & 48) == 0) {
            #pragma unroll
            for (int bi = 0; bi < 4; ++bi) {
                *(float4*)(part + (0*8 + wv)*256 + (b4*4+bi)*16 + c4*4) =
                    make_float4(aR[bi][0], aR[bi][1], aR[bi][2], aR[bi][3]);
                *(float4*)(part + (1*8 + wv)*256 + (b4*4+bi)*16 + c4*4) =
                    make_float4(aZ[bi][0], aZ[bi][1], aZ[bi][2], aZ[bi][3]);
                *(float4*)(part + (2*8 + wv)*256 + (b4*4+bi)*16 + c4*4) =
                    make_float4(aN[bi][0], aN[bi][1], aN[bi][2], aN[bi][3]);
            }
        }
        __syncthreads();
        // 768 outputs (g, b*16+c): sum over 8 waves; strided over 512 threads
        for (int e2 = tid; e2 < 768; e2 += 512) {
            int g = e2 >> 8, e = e2 & 255;
            float s = 0.f;
            #pragma unroll
            for (int w = 0; w < 8; ++w) s += part[(g*8 + w)*256 + e];
            gacc[(pass*3 + g)*256 + e] = s;
        }
        __syncthreads();
    }

    // finalize: 256 threads, one (b, c) each
    if (tid < 256) {
        int b = tid >> 4, c = tid & 15;
        int col = cb*16 + c;
        float gir = gacc[0*256 + b*16 + c] + bih[col];
        float giz = gacc[1*256 + b*16 + c] + bih[HH + col];
        float gin = gacc[2*256 + b*16 + c] + bih[2*HH + col];
        float ghr = gacc[3*256 + b*16 + c] + bhh[col];
        float ghz = gacc[4*256 + b*16 + c] + bhh[HH + col];
        float ghn = gacc[5*256 + b*16 + c] + bhh[2*HH + col];
        float r = 1.f/(1.f + __expf(-(gir + ghr)));
        float z = 1.f/(1.f + __expf(-(giz + ghz)));
        float xn = gin + r*ghn;
        float n = 1.f - 2.f/(__expf(2.f*xn) + 1.f);
        float hprev = hh[col*20 + b];
        float hnew = (1.f - z)*n + z*hprev;
        hid_out[b*HH + col] = hnew;                                    // carry (unmasked)
        out[OUT_HID_OFF + ((size_t)t*BB + b)*HH + col] = (t < olen[b]) ? hnew : 0.f;
        ws[WS_HS + col*16 + b] = hnew;                                 // [k][b] for logits
    }
}

// Logits (packed Wf tiles) + per-block argmax candidate (NO atomics).
// 500 blocks x 256 thr, 32 cols/block.
__global__ __launch_bounds__(256) void logits_kernel(
        const float* __restrict__ bf, const int* __restrict__ olen,
        float* __restrict__ ws, float* __restrict__ out, int t) {
    __shared__ float hs[HH*20];              // h_new [k][b], stride 20
    __shared__ float red[4*512];             // per-wave partials [w][b*32+c]
    __shared__ u64 am[BB*16];
    int tid = threadIdx.x;

    {   // stage h from ws [512][16] -> padded LDS
        const float4* s4 = (const float4*)(ws + WS_HS);
        #pragma unroll
        for (int j = 0; j < 8; ++j) {
            int i = tid + 256*j;             // 2048 float4
            float4 v = s4[i];
            int row = i >> 2, qo = i & 3;
            *(float4*)(hs + row*20 + qo*4) = v;
        }
    }
    __syncthreads();

    int c4 = tid & 7, kc = tid >> 3;         // 8 col-quads, 32 k-slices
    int colbase = blockIdx.x * 32;
    const float* wtile = ws + WS_WFP + (size_t)blockIdx.x*16384;
    float acc[16][4];
    #pragma unroll
    for (int bi = 0; bi < 16; ++bi) { acc[bi][0]=0.f; acc[bi][1]=0.f; acc[bi][2]=0.f; acc[bi][3]=0.f; }
    const float* wp = wtile + (size_t)kc*32 + c4*4;
    const float* hp = hs + kc*20;
    #pragma unroll 8
    for (int i = 0; i < 16; ++i) {           // k = kc + 32*i
        float4 w4 = *(const float4*)wp;
        float4 h0 = *(const float4*)(hp);
        float4 h1 = *(const float4*)(hp + 4);
        float4 h2 = *(const float4*)(hp + 8);
        float4 h3 = *(const float4*)(hp + 12);
        wp += 32 * 32;
        hp += 32 * 20;
        #define LACC(bi, hv) acc[bi][0] += (hv)*w4.x; acc[bi][1] += (hv)*w4.y; \
                             acc[bi][2] += (hv)*w4.z; acc[bi][3] += (hv)*w4.w;
        LACC(0,h0.x)  LACC(1,h0.y)  LACC(2,h0.z)  LACC(3,h0.w)
        LACC(4,h1.x)  LACC(5,h1.y)  LACC(6,h1.z)  LACC(7,h1.w)
        LACC(8,h2.x)  LACC(9,h2.y)  LACC(10,h2.z) LACC(11,h2.w)
        LACC(12,h3.x) LACC(13,h3.y) LACC(14,h3.z) LACC(15,h3.w)
        #undef LACC
    }

    // reduce over kc: in-wave lane bits 3,4,5
    #pragma unroll
    for (int bi = 0; bi < 16; ++bi)
        #pragma unroll
        for (int ci = 0; ci < 4; ++ci) {
            float v = acc[bi][ci];
            v += __shfl_xor(v, 8);
            v += __shfl_xor(v, 16);
            v += __shfl_xor(v, 32);
            acc[bi][ci] = v;
        }
    int wv = tid >> 6;
    if ((tid & 56) == 0) {   // lanes 0..7 (= c4) of each wave
        #pragma unroll
        for (int bi = 0; bi < 16; ++bi)
            *(float4*)(red + wv*512 + bi*32 + c4*4) =
                make_float4(acc[bi][0], acc[bi][1], acc[bi][2], acc[bi][3]);
    }
    __syncthreads();

    // final: 512 outputs (16b x 32c), 2 per thread
    {
        int b = tid >> 4, cp = (tid & 15) * 2;
        float2 bf2 = *(const float2*)(bf + colbase + cp);
        float v0 = bf2.x, v1 = bf2.y;
        #pragma unroll
        for (int w = 0; w < 4; ++w) {
            v0 += red[w*512 + b*32 + cp];
            v1 += red[w*512 + b*32 + cp + 1];
        }
        bool active = t < olen[b];
        float2 ov; ov.x = active ? v0 : 0.f; ov.y = active ? v1 : 0.f;
        *(float2*)(out + ((size_t)t*BB + b)*VV + colbase + cp) = ov;

        unsigned u0 = __float_as_uint(v0);
        u0 = (u0 & 0x80000000u) ? ~u0 : (u0 | 0x80000000u);
        unsigned u1 = __float_as_uint(v1);
        u1 = (u1 & 0x80000000u) ? ~u1 : (u1 | 0x80000000u);
        u64 e0 = ((u64)u0 << 32) | (u64)(0xFFFFFFFFu - (unsigned)(colbase + cp));
        u64 e1 = ((u64)u1 << 32) | (u64)(0xFFFFFFFFu - (unsigned)(colbase + cp + 1));
        am[b*16 + (tid & 15)] = e0 > e1 ? e0 : e1;
    }
    __syncthreads();
    if (tid < BB) {
        u64 m = 0ull;
        #pragma unroll
        for (int i = 0; i < 16; ++i) {
            u64 v = am[tid*16 + i];
            m = v > m ? v : m;
        }
        ((u64*)(ws + WS_CAND))[(size_t)blockIdx.x*BB + tid] = m;   // plain store
    }
}

extern "C" void kernel_launch(void* const* d_in, const int* in_sizes, int n_in,
                              void* d_out, int out_size, void* d_ws, size_t ws_size,
                              hipStream_t stream) {
    const float* mem = (const float*)d_in[0];
    const float* emb = (const float*)d_in[1];
    const float* Wq  = (const float*)d_in[2];
    const float* bq  = (const float*)d_in[3];
    const float* Wk  = (const float*)d_in[4];
    const float* bk  = (const float*)d_in[5];
    const float* Wv  = (const float*)d_in[6];
    const float* bv  = (const float*)d_in[7];
    const float* Wih = (const float*)d_in[8];
    const float* bih = (const float*)d_in[9];
    const float* Whh = (const float*)d_in[10];
    const float* bhh = (const float*)d_in[11];
    const float* Wf  = (const float*)d_in[12];
    const float* bf  = (const float*)d_in[13];
    const int* olen  = (const int*)d_in[14];
    float* out = (float*)d_out;
    float* ws  = (float*)d_ws;

    hipLaunchKernelGGL(kv_kernel, dim3(2548), dim3(256), 0, stream,
                       mem, Wk, bk, Wv, bv, Wf, ws);
    for (int t = 0; t < TT; ++t) {
        hipLaunchKernelGGL(attn_kernel, dim3(BB*NH), dim3(256), 0, stream, emb, Wq, bq, ws, t);
        hipLaunchKernelGGL(gates_kernel, dim3(32), dim3(512), 0, stream,
                           Wih, bih, Whh, bhh, olen, ws, out, t);
        hipLaunchKernelGGL(logits_kernel, dim3(500), dim3(256), 0, stream,
                           bf, olen, ws, out, t);
    }
}